// Round 5
// baseline (105.482 us; speedup 1.0000x reference)
//
#include <hip/hip_runtime.h>

// Problem constants
#define B_ 4
#define E_ 1024
#define S_ 2048
#define H_ 16
#define K_ 1024

#define NCH 32          // scan chunks along S (batch-local)
#define CS  (S_/NCH)    // 64

typedef __bf16 bf16x8 __attribute__((ext_vector_type(8)));
typedef float  f32x4  __attribute__((ext_vector_type(4)));

__device__ __forceinline__ unsigned short f2bf(float f) {
  unsigned u = __float_as_uint(f);
  u += 0x7fffu + ((u >> 16) & 1u);   // round-to-nearest-even
  return (unsigned short)(u >> 16);
}
__device__ __forceinline__ float bf2f(unsigned short h) {
  return __uint_as_float(((unsigned)h) << 16);
}

// ---------------------------------------------------------------------------
// Merged: x (B,E,S) fp32 -> Xt (B,S,E) bf16 transpose  (blockIdx.z < 4)
//       + weight fp32->bf16 conversion                  (blockIdx.z == 4)
// ---------------------------------------------------------------------------
__global__ __launch_bounds__(256)
void tc_kernel(const float* __restrict__ x, unsigned short* __restrict__ xt,
               const float* __restrict__ inw, const float* __restrict__ outw,
               unsigned short* __restrict__ w1, unsigned short* __restrict__ w2)
{
  if (blockIdx.z == 4) {
    const int per = (E_ * E_) / 4;                 // float4s per matrix
    const int fid = blockIdx.y * 32 + blockIdx.x;  // 0..511
#pragma unroll
    for (int k = 0; k < 4; ++k) {
      int i = fid * 1024 + k * 256 + threadIdx.x;  // 0 .. 2*per-1
      const float4* src = (i < per) ? (const float4*)inw : (const float4*)outw;
      unsigned short* dst = (i < per) ? w1 : w2;
      int j = (i < per) ? i : i - per;
      float4 v = src[j];
      ushort4 o;
      o.x = f2bf(v.x); o.y = f2bf(v.y); o.z = f2bf(v.z); o.w = f2bf(v.w);
      *(ushort4*)(dst + (long)j * 4) = o;
    }
    return;
  }

  __shared__ float t[64][65];
  const int b  = blockIdx.z;
  const int e0 = blockIdx.y * 64;
  const int s0 = blockIdx.x * 64;
  const int tx = threadIdx.x & 63, ty = threadIdx.x >> 6;

  const float* xp = x + ((long)b * E_ + e0) * S_ + s0;
#pragma unroll
  for (int r = 0; r < 16; ++r) {
    int row = r * 4 + ty;                          // e-offset within tile
    t[row][tx] = xp[(long)row * S_ + tx];
  }
  __syncthreads();
  unsigned short* xo = xt + ((long)b * S_ + s0) * E_ + e0;
#pragma unroll
  for (int p = 0; p < 2; ++p) {
    int s = p * 32 + (threadIdx.x >> 3);           // s-offset in tile
    int e = (threadIdx.x & 7) * 8;                 // e-offset in tile
    unsigned short v[8];
#pragma unroll
    for (int j = 0; j < 8; ++j) v[j] = f2bf(t[e + j][s]);
    *(ushort4*)(xo + (long)s * E_ + e)     = make_ushort4(v[0], v[1], v[2], v[3]);
    *(ushort4*)(xo + (long)s * E_ + e + 4) = make_ushort4(v[4], v[5], v[6], v[7]);
  }
}

// ---------------------------------------------------------------------------
// GEMM: C (8192 x 1024) = A (8192 x 1024) * Bw (1024 x 1024)^T + bias
// BM=256, BN=128, BK=64; 256 thr = 4 waves (2M x 2N), wave-tile 128x64
// (LDS traffic/FLOP law: (1/WM+1/WN) -> 96 KB per K-tile, was 160 KB).
// Double-buffered 96 KiB XOR-swizzled LDS; 32 MFMA/phase/wave; counted
// vmcnt(12) = 2 half-tiles in flight (T4); setprio (T5); XCD tiling (T1).
// VARIANT 0: C = Yt bf16 row-major + fused scan chunk partials -> part.
// VARIANT 1: C = out fp32 written transposed into (B_,E_,S_).
// ---------------------------------------------------------------------------
#define BB1 49152      // buffer 1 byte offset (48 KiB per buffer)

__device__ __forceinline__ void stage_a(char* smem, const unsigned short* __restrict__ Ab,
                                        int bb, int t, int ks, int tid, int wid) {
#pragma unroll
  for (int j = 0; j < 4; ++j) {
    int chunk = j * 256 + tid;                     // 0..1023 ; 4 chunks/row
    int row = chunk >> 2;                          // 0..255
    int cb  = (chunk & 3) << 4;
    int cbs = cb ^ (((row >> 1) & 3) << 4);        // inverse(=same) swizzle on source
    const unsigned short* src = Ab + (long)row * K_ + t * 64 + ks * 32 + (cbs >> 1);
    __builtin_amdgcn_global_load_lds(
        (const __attribute__((address_space(1))) void*)src,
        (__attribute__((address_space(3))) void*)(smem + bb + ks * 16384 + j * 4096 + wid * 1024),
        16, 0, 0);
  }
}

__device__ __forceinline__ void stage_b(char* smem, const unsigned short* __restrict__ Bb,
                                        int bb, int t, int ks, int tid, int wid) {
#pragma unroll
  for (int j = 0; j < 2; ++j) {
    int chunk = j * 256 + tid;                     // 0..511
    int row = chunk >> 2;                          // 0..127
    int cb  = (chunk & 3) << 4;
    int cbs = cb ^ (((row >> 1) & 3) << 4);
    const unsigned short* src = Bb + (long)row * K_ + t * 64 + ks * 32 + (cbs >> 1);
    __builtin_amdgcn_global_load_lds(
        (const __attribute__((address_space(1))) void*)src,
        (__attribute__((address_space(3))) void*)(smem + bb + 32768 + ks * 8192 + j * 4096 + wid * 1024),
        16, 0, 0);
  }
}

#define FENCE asm volatile("" ::: "memory")
#define BAR do { FENCE; __builtin_amdgcn_s_barrier(); FENCE; } while (0)
#define VM(n) asm volatile("s_waitcnt vmcnt(" #n ")" ::: "memory")
#define NOWAIT (void)0

// One phase: 12 ds_read_b128 (8 A + 4 B), stage next half-tile (6 gloads),
// counted vmcnt, barrier, 32 MFMA, barrier.
#define PH(bb, ks, STAGE, WAIT) do {                                        \
    bf16x8 af[8], bfv[4];                                                   \
    _Pragma("unroll")                                                       \
    for (int q = 0; q < 8; ++q) {                                           \
      int row = wm * 128 + q * 16 + lr;                                     \
      int cb = (lg * 16) ^ (((row >> 1) & 3) << 4);                         \
      af[q] = *(const bf16x8*)(smem + (bb) + (ks) * 16384 + row * 64 + cb); \
    }                                                                       \
    _Pragma("unroll")                                                       \
    for (int q = 0; q < 4; ++q) {                                           \
      int row = wn * 64 + q * 16 + lr;                                      \
      int cb = (lg * 16) ^ (((row >> 1) & 3) << 4);                         \
      bfv[q] = *(const bf16x8*)(smem + (bb) + 32768 + (ks) * 8192 + row * 64 + cb); \
    }                                                                       \
    STAGE;                                                                  \
    WAIT;                                                                   \
    BAR;                                                                    \
    asm volatile("s_waitcnt lgkmcnt(0)" ::: "memory");                      \
    __builtin_amdgcn_s_setprio(1);                                          \
    _Pragma("unroll")                                                       \
    for (int q = 0; q < 8; ++q)                                             \
      _Pragma("unroll")                                                     \
      for (int nf = 0; nf < 4; ++nf)                                        \
        acc[q][nf] = __builtin_amdgcn_mfma_f32_16x16x32_bf16(               \
            af[q], bfv[nf], acc[q][nf], 0, 0, 0);                           \
    __builtin_amdgcn_s_setprio(0);                                          \
    BAR;                                                                    \
  } while (0)

template<int VARIANT>
__global__ __launch_bounds__(256, 1)
void gemm4p(const unsigned short* __restrict__ A, const unsigned short* __restrict__ Bw,
            void* __restrict__ Cout, const float* __restrict__ bias,
            const float* __restrict__ mixw, float* __restrict__ part)
{
  extern __shared__ char smem[];
  const int tid  = threadIdx.x;
  const int lane = tid & 63, wid = tid >> 6;
  const int wm = wid >> 1, wn = wid & 1;           // 2M x 2N waves, 128x64 each
  const int lr = lane & 15, lg = lane >> 4;

  // T1 XCD-aware tiling: XCD x owns tm in {4x..4x+3} x tn in {0..7}.
  const int bid = blockIdx.x;
  const int xcd = bid & 7;
  const int j8  = bid >> 3;
  const int tm  = (xcd << 2) | (j8 & 3);           // 0..31
  const int tn  = j8 >> 2;                         // 0..7

  const unsigned short* Ab = A  + (long)tm * 256 * K_;
  const unsigned short* Bb = Bw + (long)tn * 128 * K_;

  f32x4 acc[8][4] = {};

  // Prologue: 3 half-tiles = 18 gload insts; VM(12) retires t0.ks0.
  stage_a(smem, Ab, 0,   0, 0, tid, wid);  stage_b(smem, Bb, 0,   0, 0, tid, wid);
  stage_a(smem, Ab, 0,   0, 1, tid, wid);  stage_b(smem, Bb, 0,   0, 1, tid, wid);
  stage_a(smem, Ab, BB1, 1, 0, tid, wid);  stage_b(smem, Bb, BB1, 1, 0, tid, wid);
  VM(12);
  BAR;

  for (int t = 0; t < 14; ++t) {
    const int bb = (t & 1) ? BB1 : 0;
    const int nb = (t & 1) ? 0 : BB1;
    PH(bb, 0, { stage_a(smem, Ab, nb, t + 1, 1, tid, wid);
                stage_b(smem, Bb, nb, t + 1, 1, tid, wid); }, VM(12));
    PH(bb, 1, { stage_a(smem, Ab, bb, t + 2, 0, tid, wid);
                stage_b(smem, Bb, bb, t + 2, 0, tid, wid); }, VM(12));
  }
  // t=14 (buf0), t=15 (buf1): drain VM(12) -> VM(6) -> VM(0).
  PH(0, 0, { stage_a(smem, Ab, BB1, 15, 1, tid, wid);
             stage_b(smem, Bb, BB1, 15, 1, tid, wid); }, VM(12));
  PH(0,   1, NOWAIT, VM(6));
  PH(BB1, 0, NOWAIT, VM(0));
  PH(BB1, 1, NOWAIT, NOWAIT);

  // Epilogue. C/D frag: col = lane&15, row = (lane>>4)*4 + j  [m89/m91]
#pragma unroll
  for (int nf = 0; nf < 4; ++nf) {
    const int c = tn * 128 + wn * 64 + nf * 16 + lr;
    const float bv = bias[c];
    if constexpr (VARIANT == 0) {
      const int h  = c >> 6;                       // head for this channel
      const int bt = tm >> 3;                      // batch
      const int sb = ((tm & 7) << 8) + wm * 128;   // batch-local s of wave base
      float sm0 = 0.f, sm1 = 0.f;
#pragma unroll
      for (int mf = 0; mf < 8; ++mf) {
#pragma unroll
        for (int j = 0; j < 4; ++j) {
          const int sl = sb + mf * 16 + lg * 4 + j;
          float v = acc[mf][nf][j] + bv;
          ((unsigned short*)Cout)[((long)bt * S_ + sl) * E_ + c] = f2bf(v);
          float w = (h < 8) ? v : v * mixw[h * S_ + sl];
          if (mf < 4) sm0 += w; else sm1 += w;
        }
      }
      // reduce over lg group (lanes lg*16+lr) -> 64-row chunk sums
      sm0 += __shfl_xor(sm0, 16, 64);  sm0 += __shfl_xor(sm0, 32, 64);
      sm1 += __shfl_xor(sm1, 16, 64);  sm1 += __shfl_xor(sm1, 32, 64);
      if (lg == 0) {
        const int ch0 = ((tm & 7) << 2) + wm * 2;  // batch-local chunk of sm0
        part[((long)bt * NCH + ch0)     * E_ + c] = sm0;
        part[((long)bt * NCH + ch0 + 1) * E_ + c] = sm1;
      }
    } else {
#pragma unroll
      for (int mf = 0; mf < 8; ++mf) {
        const int r0 = tm * 256 + wm * 128 + mf * 16 + lg * 4;
        const int s = r0 & (S_ - 1);
        const int b = r0 >> 11;                    // 256-row tile never crosses batch
        float4 v;
        v.x = acc[mf][nf][0] + bv; v.y = acc[mf][nf][1] + bv;
        v.z = acc[mf][nf][2] + bv; v.w = acc[mf][nf][3] + bv;
        *(float4*)((float*)Cout + ((long)b * E_ + c) * S_ + s) = v;
      }
    }
  }
}

// ---------------------------------------------------------------------------
// scan_final: causal prefix combine using chunk partials from GEMM1 epilogue.
// ---------------------------------------------------------------------------
__global__ __launch_bounds__(256)
void scan_final(const unsigned short* __restrict__ yt, const float* __restrict__ mixw,
                const float* __restrict__ mixb, const float* __restrict__ part,
                unsigned short* __restrict__ zt)
{
  const int b  = blockIdx.z;
  const int c  = blockIdx.y * 256 + threadIdx.x;
  const int ch = blockIdx.x;
  const int h  = c >> 6;
  float acc = 0.f;
  for (int p = 0; p < ch; ++p) acc += part[((long)b * NCH + p) * E_ + c];
  const unsigned short* yp = yt + ((long)b * S_ + ch * CS) * E_ + c;
  unsigned short*       zp = zt + ((long)b * S_ + ch * CS) * E_ + c;
  const float* mw = mixw + (long)h * S_ + ch * CS;
  const float* mb = mixb + (long)h * S_ + ch * CS;
  if (h < 8) {
    for (int s = 0; s < CS; ++s) {
      acc += bf2f(yp[(long)s * E_]);
      zp[(long)s * E_] = f2bf(fmaf(acc, mw[s], mb[s]));
    }
  } else {
    for (int s = 0; s < CS; ++s) {
      acc += bf2f(yp[(long)s * E_]) * mw[s];
      zp[(long)s * E_] = f2bf(acc + mb[s]);
    }
  }
}

// ---------------------------------------------------------------------------
extern "C" void kernel_launch(void* const* d_in, const int* in_sizes, int n_in,
                              void* d_out, int out_size, void* d_ws, size_t ws_size,
                              hipStream_t stream)
{
  (void)in_sizes; (void)n_in; (void)out_size; (void)ws_size;
  const float* x     = (const float*)d_in[0];
  const float* in_w  = (const float*)d_in[1];
  const float* in_b  = (const float*)d_in[2];
  const float* out_w = (const float*)d_in[3];
  const float* out_b = (const float*)d_in[4];
  const float* mix_w = (const float*)d_in[5];
  const float* mix_b = (const float*)d_in[6];

  char* ws = (char*)d_ws;
  unsigned short* Xt  = (unsigned short*)(ws);                            // 16 MB (reused as Zt)
  unsigned short* Yt  = (unsigned short*)(ws + (size_t)16 * 1024 * 1024); // 16 MB
  unsigned short* W1b = (unsigned short*)(ws + (size_t)32 * 1024 * 1024); // 2 MB
  unsigned short* W2b = (unsigned short*)(ws + (size_t)34 * 1024 * 1024); // 2 MB
  float*          part = (float*)(ws + (size_t)36 * 1024 * 1024);         // 512 KB
  unsigned short* Zt  = Xt;

  hipFuncSetAttribute((const void*)gemm4p<0>, hipFuncAttributeMaxDynamicSharedMemorySize, 98304);
  hipFuncSetAttribute((const void*)gemm4p<1>, hipFuncAttributeMaxDynamicSharedMemorySize, 98304);

  // transpose+convert (z<4: transpose batch z; z==4: weight convert)
  tc_kernel<<<dim3(S_ / 64, E_ / 64, 5), 256, 0, stream>>>(x, Xt, in_w, out_w, W1b, W2b);

  // in_proj + fused scan partials: Yt = Xt * W1b^T + in_b ; part = chunk sums
  gemm4p<0><<<dim3(256), 256, 98304, stream>>>(Xt, W1b, Yt, in_b, mix_w, part);

  scan_final<<<dim3(NCH, E_ / 256, B_), 256, 0, stream>>>(Yt, mix_w, mix_b, part, Zt);

  // out_proj: out(b,e,s) = transposed-write of Zt * W2b^T + out_b
  gemm4p<1><<<dim3(256), 256, 98304, stream>>>(Zt, W2b, d_out, out_b, nullptr, nullptr);
}

// Round 6
// 96.808 us; speedup vs baseline: 1.0896x; 1.0896x over previous
//
#include <hip/hip_runtime.h>

// Problem constants
#define B_ 4
#define E_ 1024
#define S_ 2048
#define H_ 16
#define K_ 1024

#define NCH 32          // scan chunks along S (batch-local)
#define CS  (S_/NCH)    // 64

typedef __bf16 bf16x8 __attribute__((ext_vector_type(8)));
typedef float  f32x4  __attribute__((ext_vector_type(4)));

__device__ __forceinline__ unsigned short f2bf(float f) {
  unsigned u = __float_as_uint(f);
  u += 0x7fffu + ((u >> 16) & 1u);   // round-to-nearest-even
  return (unsigned short)(u >> 16);
}
__device__ __forceinline__ float bf2f(unsigned short h) {
  return __uint_as_float(((unsigned)h) << 16);
}

// ---------------------------------------------------------------------------
// Merged: x (B,E,S) fp32 -> Xt (B,S,E) bf16 transpose  (blockIdx.z < 4)
//       + weight fp32->bf16 conversion                  (blockIdx.z == 4)
// ---------------------------------------------------------------------------
__global__ __launch_bounds__(256)
void tc_kernel(const float* __restrict__ x, unsigned short* __restrict__ xt,
               const float* __restrict__ inw, const float* __restrict__ outw,
               unsigned short* __restrict__ w1, unsigned short* __restrict__ w2)
{
  if (blockIdx.z == 4) {
    const int per = (E_ * E_) / 4;                 // float4s per matrix
    const int fid = blockIdx.y * 32 + blockIdx.x;  // 0..511
#pragma unroll
    for (int k = 0; k < 4; ++k) {
      int i = fid * 1024 + k * 256 + threadIdx.x;  // 0 .. 2*per-1
      const float4* src = (i < per) ? (const float4*)inw : (const float4*)outw;
      unsigned short* dst = (i < per) ? w1 : w2;
      int j = (i < per) ? i : i - per;
      float4 v = src[j];
      ushort4 o;
      o.x = f2bf(v.x); o.y = f2bf(v.y); o.z = f2bf(v.z); o.w = f2bf(v.w);
      *(ushort4*)(dst + (long)j * 4) = o;
    }
    return;
  }

  __shared__ float t[64][65];
  const int b  = blockIdx.z;
  const int e0 = blockIdx.y * 64;
  const int s0 = blockIdx.x * 64;
  const int tx = threadIdx.x & 63, ty = threadIdx.x >> 6;

  const float* xp = x + ((long)b * E_ + e0) * S_ + s0;
#pragma unroll
  for (int r = 0; r < 16; ++r) {
    int row = r * 4 + ty;                          // e-offset within tile
    t[row][tx] = xp[(long)row * S_ + tx];
  }
  __syncthreads();
  unsigned short* xo = xt + ((long)b * S_ + s0) * E_ + e0;
#pragma unroll
  for (int p = 0; p < 2; ++p) {
    int s = p * 32 + (threadIdx.x >> 3);           // s-offset in tile
    int e = (threadIdx.x & 7) * 8;                 // e-offset in tile
    unsigned short v[8];
#pragma unroll
    for (int j = 0; j < 8; ++j) v[j] = f2bf(t[e + j][s]);
    *(ushort4*)(xo + (long)s * E_ + e)     = make_ushort4(v[0], v[1], v[2], v[3]);
    *(ushort4*)(xo + (long)s * E_ + e + 4) = make_ushort4(v[4], v[5], v[6], v[7]);
  }
}

// ---------------------------------------------------------------------------
// m97-style GEMM: C (8192 x 1024) = A (8192 x 1024) * Bw (1024 x 1024)^T + b
// BM=BN=128, BK=64; 256 thr = 4 waves (2x2), wave-tile 64x64; 32 KB
// single-buffered LDS; plain __syncthreads; compiler-scheduled waits.
// Latency hiding comes from 2 co-resident blocks/CU slipping against each
// other (m114 overlap), NOT from explicit scheduling (R5 post-mortem:
// lockstep vmcnt/barrier phases at 1 wave/SIMD = 12% MfmaUtil, all idle).
// T1 XCD tiling: xcd=bid&7 owns tm in {8x..8x+7} x all tn; per-XCD L2
// working set = 2 MB A + 2 MB B = 4 MB.
// VARIANT 0: C = Yt bf16 row-major + fused scan chunk partials -> part.
// VARIANT 1: C = out fp32 written transposed into (B_,E_,S_).
// ---------------------------------------------------------------------------
template<int VARIANT>
__global__ __launch_bounds__(256, 2)
void gemm_m97(const unsigned short* __restrict__ A, const unsigned short* __restrict__ Bw,
              void* __restrict__ Cout, const float* __restrict__ bias,
              const float* __restrict__ mixw, float* __restrict__ part)
{
  __shared__ unsigned short As[128 * 64];
  __shared__ unsigned short Bs[128 * 64];

  const int tid  = threadIdx.x;
  const int lane = tid & 63, wid = tid >> 6;
  const int wm = wid >> 1, wn = wid & 1;           // 2x2 waves, 64x64 each
  const int lr = lane & 15, lg = lane >> 4;

  // T1: grid 512 = 8 XCD x 64; same-tm blocks land on one XCD.
  const int bid = blockIdx.x;
  const int xcd = bid & 7;
  const int j   = bid >> 3;                        // 0..63
  const int tm  = (xcd << 3) | (j & 7);            // 0..63
  const int tn  = j >> 3;                          // 0..7

  const unsigned short* Ab = A  + (long)tm * 128 * K_;
  const unsigned short* Bb = Bw + (long)tn * 128 * K_;

  f32x4 acc[4][4] = {};

  for (int kt = 0; kt < K_; kt += 64) {
    // stage A,B tiles: 16 KB each = 4 insts x 256 thr x 16 B
#pragma unroll
    for (int i = 0; i < 4; ++i) {
      int chunk = i * 256 + tid;                   // 16B chunk id; 8 chunks/row
      int row = chunk >> 3;
      int kc  = (chunk & 7) << 3;
      int wbase = (i * 256 + wid * 64) << 3;       // wave-uniform LDS elem base
      __builtin_amdgcn_global_load_lds(
          (const __attribute__((address_space(1))) void*)(Ab + (long)row * K_ + kt + kc),
          (__attribute__((address_space(3))) void*)(As + wbase), 16, 0, 0);
      __builtin_amdgcn_global_load_lds(
          (const __attribute__((address_space(1))) void*)(Bb + (long)row * K_ + kt + kc),
          (__attribute__((address_space(3))) void*)(Bs + wbase), 16, 0, 0);
    }
    __syncthreads();

#pragma unroll
    for (int ks = 0; ks < 2; ++ks) {
      const int koff = ks * 32 + lg * 8;
      bf16x8 af[4], bfv[4];
#pragma unroll
      for (int mf = 0; mf < 4; ++mf)
        af[mf] = *(const bf16x8*)(As + (wm * 64 + mf * 16 + lr) * 64 + koff);
#pragma unroll
      for (int nf = 0; nf < 4; ++nf)
        bfv[nf] = *(const bf16x8*)(Bs + (wn * 64 + nf * 16 + lr) * 64 + koff);
#pragma unroll
      for (int mf = 0; mf < 4; ++mf)
#pragma unroll
        for (int nf = 0; nf < 4; ++nf)
          acc[mf][nf] = __builtin_amdgcn_mfma_f32_16x16x32_bf16(
              af[mf], bfv[nf], acc[mf][nf], 0, 0, 0);
    }
    __syncthreads();
  }

  // Epilogue. C/D frag: col = lane&15, row = (lane>>4)*4 + j  [m89/m91]
  if constexpr (VARIANT == 0) {
    const int bt = tm >> 4;                        // batch (16 m-tiles/batch)
    const int sb = ((tm & 15) << 7) + wm * 64;     // batch-local s of wave base
    const int ch = sb >> 6;                        // 64-row chunk id (wave = 1 chunk)
#pragma unroll
    for (int nf = 0; nf < 4; ++nf) {
      const int c = tn * 128 + wn * 64 + nf * 16 + lr;
      const float bv = bias[c];
      const int h = c >> 6;
      float sm = 0.f;
#pragma unroll
      for (int mf = 0; mf < 4; ++mf) {
#pragma unroll
        for (int jj = 0; jj < 4; ++jj) {
          const int sl = sb + mf * 16 + lg * 4 + jj;
          float v = acc[mf][nf][jj] + bv;
          ((unsigned short*)Cout)[((long)bt * S_ + sl) * E_ + c] = f2bf(v);
          sm += (h < 8) ? v : v * mixw[h * S_ + sl];
        }
      }
      // reduce over lg group (lanes lg*16+lr) -> full 64-row chunk sum
      sm += __shfl_xor(sm, 16, 64);
      sm += __shfl_xor(sm, 32, 64);
      if (lg == 0) part[((long)bt * NCH + ch) * E_ + c] = sm;
    }
  } else {
#pragma unroll
    for (int nf = 0; nf < 4; ++nf) {
      const int c = tn * 128 + wn * 64 + nf * 16 + lr;
      const float bv = bias[c];
#pragma unroll
      for (int mf = 0; mf < 4; ++mf) {
        const int r0 = tm * 128 + wm * 64 + mf * 16 + lg * 4;
        const int s = r0 & (S_ - 1);
        const int b = r0 >> 11;
        float4 v;
        v.x = acc[mf][nf][0] + bv; v.y = acc[mf][nf][1] + bv;
        v.z = acc[mf][nf][2] + bv; v.w = acc[mf][nf][3] + bv;
        *(float4*)((float*)Cout + ((long)b * E_ + c) * S_ + s) = v;
      }
    }
  }
}

// ---------------------------------------------------------------------------
// scan_final: causal prefix combine using chunk partials from GEMM1 epilogue.
//   h < 8 : z[s,c] = mix_w[h,s] * (prior-chunk sums + intra-chunk cumsum)
//   h >= 8: z[s,c] = (prior weighted sums + intra-chunk weighted cumsum)
// ---------------------------------------------------------------------------
__global__ __launch_bounds__(256)
void scan_final(const unsigned short* __restrict__ yt, const float* __restrict__ mixw,
                const float* __restrict__ mixb, const float* __restrict__ part,
                unsigned short* __restrict__ zt)
{
  const int b  = blockIdx.z;
  const int c  = blockIdx.y * 256 + threadIdx.x;
  const int ch = blockIdx.x;
  const int h  = c >> 6;
  float acc = 0.f;
  for (int p = 0; p < ch; ++p) acc += part[((long)b * NCH + p) * E_ + c];
  const unsigned short* yp = yt + ((long)b * S_ + ch * CS) * E_ + c;
  unsigned short*       zp = zt + ((long)b * S_ + ch * CS) * E_ + c;
  const float* mw = mixw + (long)h * S_ + ch * CS;
  const float* mb = mixb + (long)h * S_ + ch * CS;
  if (h < 8) {
    for (int s = 0; s < CS; ++s) {
      acc += bf2f(yp[(long)s * E_]);
      zp[(long)s * E_] = f2bf(fmaf(acc, mw[s], mb[s]));
    }
  } else {
    for (int s = 0; s < CS; ++s) {
      acc += bf2f(yp[(long)s * E_]) * mw[s];
      zp[(long)s * E_] = f2bf(acc + mb[s]);
    }
  }
}

// ---------------------------------------------------------------------------
extern "C" void kernel_launch(void* const* d_in, const int* in_sizes, int n_in,
                              void* d_out, int out_size, void* d_ws, size_t ws_size,
                              hipStream_t stream)
{
  (void)in_sizes; (void)n_in; (void)out_size; (void)ws_size;
  const float* x     = (const float*)d_in[0];
  const float* in_w  = (const float*)d_in[1];
  const float* in_b  = (const float*)d_in[2];
  const float* out_w = (const float*)d_in[3];
  const float* out_b = (const float*)d_in[4];
  const float* mix_w = (const float*)d_in[5];
  const float* mix_b = (const float*)d_in[6];

  char* ws = (char*)d_ws;
  unsigned short* Xt  = (unsigned short*)(ws);                            // 16 MB (reused as Zt)
  unsigned short* Yt  = (unsigned short*)(ws + (size_t)16 * 1024 * 1024); // 16 MB
  unsigned short* W1b = (unsigned short*)(ws + (size_t)32 * 1024 * 1024); // 2 MB
  unsigned short* W2b = (unsigned short*)(ws + (size_t)34 * 1024 * 1024); // 2 MB
  float*          part = (float*)(ws + (size_t)36 * 1024 * 1024);         // 512 KB
  unsigned short* Zt  = Xt;

  // transpose+convert (z<4: transpose batch z; z==4: weight convert)
  tc_kernel<<<dim3(S_ / 64, E_ / 64, 5), 256, 0, stream>>>(x, Xt, in_w, out_w, W1b, W2b);

  // in_proj + fused scan partials: Yt = Xt * W1b^T + in_b ; part = chunk sums
  gemm_m97<0><<<dim3(512), 256, 0, stream>>>(Xt, W1b, Yt, in_b, mix_w, part);

  scan_final<<<dim3(NCH, E_ / 256, B_), 256, 0, stream>>>(Yt, mix_w, mix_b, part, Zt);

  // out_proj: out(b,e,s) = transposed-write of Zt * W2b^T + out_b
  gemm_m97<1><<<dim3(512), 256, 0, stream>>>(Zt, W2b, d_out, out_b, nullptr, nullptr);
}

// Round 7
// 78.602 us; speedup vs baseline: 1.3420x; 1.2316x over previous
//
#include <hip/hip_runtime.h>

// Problem constants
#define B_ 4
#define E_ 1024
#define S_ 2048
#define H_ 16
#define K_ 1024

#define NCH 32          // scan chunks along S (batch-local)
#define CS  (S_/NCH)    // 64

typedef __bf16 bf16x8 __attribute__((ext_vector_type(8)));
typedef float  f32x4  __attribute__((ext_vector_type(4)));

#define AS1 __attribute__((address_space(1)))
#define AS3 __attribute__((address_space(3)))

__device__ __forceinline__ unsigned short f2bf(float f) {
  unsigned u = __float_as_uint(f);
  u += 0x7fffu + ((u >> 16) & 1u);   // round-to-nearest-even
  return (unsigned short)(u >> 16);
}
__device__ __forceinline__ float bf2f(unsigned short h) {
  return __uint_as_float(((unsigned)h) << 16);
}

// ---------------------------------------------------------------------------
// Merged: x (B,E,S) fp32 -> Xt (B,S,E) bf16 transpose  (blockIdx.z < 4)
//       + weight fp32->bf16 conversion                  (blockIdx.z == 4)
// ---------------------------------------------------------------------------
__global__ __launch_bounds__(256)
void tc_kernel(const float* __restrict__ x, unsigned short* __restrict__ xt,
               const float* __restrict__ inw, const float* __restrict__ outw,
               unsigned short* __restrict__ w1, unsigned short* __restrict__ w2)
{
  if (blockIdx.z == 4) {
    const int per = (E_ * E_) / 4;                 // float4s per matrix
    const int fid = blockIdx.y * 32 + blockIdx.x;  // 0..511
#pragma unroll
    for (int k = 0; k < 4; ++k) {
      int i = fid * 1024 + k * 256 + threadIdx.x;  // 0 .. 2*per-1
      const float4* src = (i < per) ? (const float4*)inw : (const float4*)outw;
      unsigned short* dst = (i < per) ? w1 : w2;
      int j = (i < per) ? i : i - per;
      float4 v = src[j];
      ushort4 o;
      o.x = f2bf(v.x); o.y = f2bf(v.y); o.z = f2bf(v.z); o.w = f2bf(v.w);
      *(ushort4*)(dst + (long)j * 4) = o;
    }
    return;
  }

  __shared__ float t[64][65];
  const int b  = blockIdx.z;
  const int e0 = blockIdx.y * 64;
  const int s0 = blockIdx.x * 64;
  const int tx = threadIdx.x & 63, ty = threadIdx.x >> 6;

  const float* xp = x + ((long)b * E_ + e0) * S_ + s0;
#pragma unroll
  for (int r = 0; r < 16; ++r) {
    int row = r * 4 + ty;                          // e-offset within tile
    t[row][tx] = xp[(long)row * S_ + tx];
  }
  __syncthreads();
  unsigned short* xo = xt + ((long)b * S_ + s0) * E_ + e0;
#pragma unroll
  for (int p = 0; p < 2; ++p) {
    int s = p * 32 + (threadIdx.x >> 3);           // s-offset in tile
    int e = (threadIdx.x & 7) * 8;                 // e-offset in tile
    unsigned short v[8];
#pragma unroll
    for (int j = 0; j < 8; ++j) v[j] = f2bf(t[e + j][s]);
    *(ushort4*)(xo + (long)s * E_ + e)     = make_ushort4(v[0], v[1], v[2], v[3]);
    *(ushort4*)(xo + (long)s * E_ + e + 4) = make_ushort4(v[4], v[5], v[6], v[7]);
  }
}

// ---------------------------------------------------------------------------
// GEMM: C (8192 x 1024) = A (8192 x 1024) * Bw (1024 x 1024)^T + bias
// 128x128 tile, BK=64, 512 thr = 8 waves (2M x 4N, wave-tile 64x32).
// 32 KB single-buffered XOR-swizzled LDS; plain 2-barrier loop with
// compiler-scheduled waits. Occupancy is the lever this round: 2 blocks/CU
// x 8 waves = 16 waves/CU (4/SIMD) -- every prior round ran <=2/SIMD and
// was latency-bound with all pipes <20% (R5 profile). T1 XCD tiling.
// VARIANT 0: C = Yt bf16 row-major + fused scan chunk partials -> part.
// VARIANT 1: C = out fp32 written transposed into (B_,E_,S_).
// ---------------------------------------------------------------------------
__device__ __forceinline__ void stage128(char* lds, const unsigned short* __restrict__ src_base,
                                         int kt, int ks, int tid) {
  // 512 thr x 16B = 8KB = half-tile [128 rows][32 k], swizzled source (T2
  // both-sides rule: linear LDS dest, inverse-swz global source).
  int row = tid >> 2;                              // 0..127
  int cb  = (tid & 3) << 4;                        // byte col in 64B half-row
  int cbs = cb ^ (((row >> 1) & 3) << 4);
  const unsigned short* src = src_base + (long)row * K_ + kt + ks * 32 + (cbs >> 1);
  __builtin_amdgcn_global_load_lds((const AS1 void*)src,
      (AS3 void*)(lds + ks * 8192 + tid * 16), 16, 0, 0);
}

template<int VARIANT>
__global__ __launch_bounds__(512, 4)
void gemm_hw(const unsigned short* __restrict__ A, const unsigned short* __restrict__ Bw,
             void* __restrict__ Cout, const float* __restrict__ bias,
             const float* __restrict__ mixw, float* __restrict__ part)
{
  __shared__ char As[16384];                       // [2(ks)][128][32] bf16 swz
  __shared__ char Bs[16384];

  const int tid  = threadIdx.x;
  const int lane = tid & 63, wid = tid >> 6;
  const int wm = wid >> 2, wn = wid & 3;           // 2M x 4N waves, 64x32 each
  const int lr = lane & 15, lg = lane >> 4;

  // T1: grid 512 = 8 XCD x 64; XCD x owns tm in {8x..8x+7} x all 8 tn.
  const int bid = blockIdx.x;
  const int xcd = bid & 7;
  const int j   = bid >> 3;                        // 0..63
  const int tm  = (xcd << 3) | (j & 7);            // 0..63
  const int tn  = j >> 3;                          // 0..7

  const unsigned short* Ab = A  + (long)tm * 128 * K_;
  const unsigned short* Bb = Bw + (long)tn * 128 * K_;

  f32x4 acc[4][2] = {};

  for (int kt = 0; kt < K_; kt += 64) {
    stage128(As, Ab, kt, 0, tid);
    stage128(As, Ab, kt, 1, tid);
    stage128(Bs, Bb, kt, 0, tid);
    stage128(Bs, Bb, kt, 1, tid);
    __syncthreads();

#pragma unroll
    for (int ks = 0; ks < 2; ++ks) {
      bf16x8 af[4], bfv[2];
#pragma unroll
      for (int mf = 0; mf < 4; ++mf) {
        int row = wm * 64 + mf * 16 + lr;
        int cb  = (lg * 16) ^ (((row >> 1) & 3) << 4);
        af[mf] = *(const bf16x8*)(As + ks * 8192 + row * 64 + cb);
      }
#pragma unroll
      for (int nf = 0; nf < 2; ++nf) {
        int row = wn * 32 + nf * 16 + lr;
        int cb  = (lg * 16) ^ (((row >> 1) & 3) << 4);
        bfv[nf] = *(const bf16x8*)(Bs + ks * 8192 + row * 64 + cb);
      }
#pragma unroll
      for (int mf = 0; mf < 4; ++mf)
#pragma unroll
        for (int nf = 0; nf < 2; ++nf)
          acc[mf][nf] = __builtin_amdgcn_mfma_f32_16x16x32_bf16(
              af[mf], bfv[nf], acc[mf][nf], 0, 0, 0);
    }
    __syncthreads();
  }

  // Epilogue. C/D frag: col = lane&15, row = (lane>>4)*4 + j  [m89/m91]
  if constexpr (VARIANT == 0) {
    const int bt = tm >> 4;                        // batch (16 m-tiles/batch)
    const int sb = ((tm & 15) << 7) + wm * 64;     // batch-local s of wave base
    const int ch = ((tm & 15) << 1) + wm;          // 64-row chunk (1 per wave)
#pragma unroll
    for (int nf = 0; nf < 2; ++nf) {
      const int c = tn * 128 + wn * 32 + nf * 16 + lr;
      const float bv = bias[c];
      const int h = c >> 6;
      float sm = 0.f;
#pragma unroll
      for (int mf = 0; mf < 4; ++mf) {
#pragma unroll
        for (int jj = 0; jj < 4; ++jj) {
          const int sl = sb + mf * 16 + lg * 4 + jj;
          float v = acc[mf][nf][jj] + bv;
          ((unsigned short*)Cout)[((long)bt * S_ + sl) * E_ + c] = f2bf(v);
          sm += (h < 8) ? v : v * mixw[h * S_ + sl];
        }
      }
      sm += __shfl_xor(sm, 16, 64);
      sm += __shfl_xor(sm, 32, 64);
      if (lg == 0) part[((long)bt * NCH + ch) * E_ + c] = sm;
    }
  } else {
#pragma unroll
    for (int nf = 0; nf < 2; ++nf) {
      const int c = tn * 128 + wn * 32 + nf * 16 + lr;
      const float bv = bias[c];
#pragma unroll
      for (int mf = 0; mf < 4; ++mf) {
        const int r0 = tm * 128 + wm * 64 + mf * 16 + lg * 4;
        const int s = r0 & (S_ - 1);
        const int b = r0 >> 11;
        float4 v;
        v.x = acc[mf][nf][0] + bv; v.y = acc[mf][nf][1] + bv;
        v.z = acc[mf][nf][2] + bv; v.w = acc[mf][nf][3] + bv;
        *(float4*)((float*)Cout + ((long)b * E_ + c) * S_ + s) = v;
      }
    }
  }
}

// ---------------------------------------------------------------------------
// scan_final: causal prefix combine using chunk partials from GEMM1 epilogue.
//   h < 8 : z[s,c] = mix_w[h,s] * (prior-chunk sums + intra-chunk cumsum)
//   h >= 8: z[s,c] = (prior weighted sums + intra-chunk weighted cumsum)
// ---------------------------------------------------------------------------
__global__ __launch_bounds__(256)
void scan_final(const unsigned short* __restrict__ yt, const float* __restrict__ mixw,
                const float* __restrict__ mixb, const float* __restrict__ part,
                unsigned short* __restrict__ zt)
{
  const int b  = blockIdx.z;
  const int c  = blockIdx.y * 256 + threadIdx.x;
  const int ch = blockIdx.x;
  const int h  = c >> 6;
  float acc = 0.f;
  for (int p = 0; p < ch; ++p) acc += part[((long)b * NCH + p) * E_ + c];
  const unsigned short* yp = yt + ((long)b * S_ + ch * CS) * E_ + c;
  unsigned short*       zp = zt + ((long)b * S_ + ch * CS) * E_ + c;
  const float* mw = mixw + (long)h * S_ + ch * CS;
  const float* mb = mixb + (long)h * S_ + ch * CS;
  if (h < 8) {
    for (int s = 0; s < CS; ++s) {
      acc += bf2f(yp[(long)s * E_]);
      zp[(long)s * E_] = f2bf(fmaf(acc, mw[s], mb[s]));
    }
  } else {
    for (int s = 0; s < CS; ++s) {
      acc += bf2f(yp[(long)s * E_]) * mw[s];
      zp[(long)s * E_] = f2bf(acc + mb[s]);
    }
  }
}

// ---------------------------------------------------------------------------
extern "C" void kernel_launch(void* const* d_in, const int* in_sizes, int n_in,
                              void* d_out, int out_size, void* d_ws, size_t ws_size,
                              hipStream_t stream)
{
  (void)in_sizes; (void)n_in; (void)out_size; (void)ws_size;
  const float* x     = (const float*)d_in[0];
  const float* in_w  = (const float*)d_in[1];
  const float* in_b  = (const float*)d_in[2];
  const float* out_w = (const float*)d_in[3];
  const float* out_b = (const float*)d_in[4];
  const float* mix_w = (const float*)d_in[5];
  const float* mix_b = (const float*)d_in[6];

  char* ws = (char*)d_ws;
  unsigned short* Xt  = (unsigned short*)(ws);                            // 16 MB (reused as Zt)
  unsigned short* Yt  = (unsigned short*)(ws + (size_t)16 * 1024 * 1024); // 16 MB
  unsigned short* W1b = (unsigned short*)(ws + (size_t)32 * 1024 * 1024); // 2 MB
  unsigned short* W2b = (unsigned short*)(ws + (size_t)34 * 1024 * 1024); // 2 MB
  float*          part = (float*)(ws + (size_t)36 * 1024 * 1024);         // 512 KB
  unsigned short* Zt  = Xt;

  // transpose+convert (z<4: transpose batch z; z==4: weight convert)
  tc_kernel<<<dim3(S_ / 64, E_ / 64, 5), 256, 0, stream>>>(x, Xt, in_w, out_w, W1b, W2b);

  // in_proj + fused scan partials: Yt = Xt * W1b^T + in_b ; part = chunk sums
  gemm_hw<0><<<dim3(512), 512, 0, stream>>>(Xt, W1b, Yt, in_b, mix_w, part);

  scan_final<<<dim3(NCH, E_ / 256, B_), 256, 0, stream>>>(Yt, mix_w, mix_b, part, Zt);

  // out_proj: out(b,e,s) = transposed-write of Zt * W2b^T + out_b
  gemm_hw<1><<<dim3(512), 512, 0, stream>>>(Zt, W2b, d_out, out_b, nullptr, nullptr);
}